// Round 7
// baseline (112.898 us; speedup 1.0000x reference)
//
#include <hip/hip_runtime.h>
#include <hip/hip_bf16.h>
#include <stdint.h>

#define B_  256
#define T_  1024
#define F_  16
#define N_  1024

typedef short bf16x8 __attribute__((ext_vector_type(8)));
typedef float f32x4  __attribute__((ext_vector_type(4)));

static __device__ __forceinline__ unsigned short f2bf(float x) {
  unsigned u = __builtin_bit_cast(unsigned, x);
  u += 0x7fffu + ((u >> 16) & 1u);
  return (unsigned short)(u >> 16);
}
static __device__ __forceinline__ float bf2f(unsigned short h) {
  unsigned u = ((unsigned)h) << 16;
  return __builtin_bit_cast(float, u);
}

// ---- pass 1: x[b][t][f] fp32 -> At2 fragment layout bf16 ----
// At2 element (f,b,k) at ((f*32+kc)*16+rb)*512 + lane*8 + j, where
// kc=k>>5, rb=b>>4, lane=((k>>3)&3)*16 + (b&15), j=k&7.
__global__ __launch_bounds__(256) void prep2_kernel(const float* __restrict__ x,
                                                    unsigned short* __restrict__ At2) {
  __shared__ unsigned short ld[16 * 1028];   // [b_local][t_local*16+f], pitch 1028
  const int rb = blockIdx.x >> 4, tc = blockIdx.x & 15;
  const int tid = threadIdx.x;
  const int tl = tid >> 2;            // t-local 0..63
  const int f4 = (tid & 3) * 4;       // f quad
#pragma unroll
  for (int i = 0; i < 16; ++i) {
    const float* src = x + (((size_t)(rb * 16 + i) * T_) + tc * 64 + tl) * F_ + f4;
    float4 v = *(const float4*)src;
    uint2 pk;
    pk.x = (unsigned)f2bf(v.x) | ((unsigned)f2bf(v.y) << 16);
    pk.y = (unsigned)f2bf(v.z) | ((unsigned)f2bf(v.w) << 16);
    *(uint2*)&ld[i * 1028 + tl * 16 + f4] = pk;
  }
  __syncthreads();
  const int w = tid >> 6, l = tid & 63;
#pragma unroll
  for (int it = 0; it < 8; ++it) {
    const int c = it * 4 + w;          // 0..31 = (f, kcl)
    const int f = c >> 1, kcl = c & 1;
    unsigned short t16[8];
#pragma unroll
    for (int j = 0; j < 8; ++j)
      t16[j] = ld[(l & 15) * 1028 + (kcl * 32 + ((l >> 4) * 8) + j) * 16 + f];
    uint4 q;
    q.x = (unsigned)t16[0] | ((unsigned)t16[1] << 16);
    q.y = (unsigned)t16[2] | ((unsigned)t16[3] << 16);
    q.z = (unsigned)t16[4] | ((unsigned)t16[5] << 16);
    q.w = (unsigned)t16[6] | ((unsigned)t16[7] << 16);
    *(uint4*)(At2 + (((size_t)(f * 32 + tc * 2 + kcl) * 16 + rb) << 9) + l * 8) = q;
  }
}

// ---- pass 2: fused GEMM, EBN=64 (4 n-subtiles/block, A-frags reused x4) ----
// acc[b,n] = sum_t x_bf16[b,t,f] * V[f,t,n]
// V[t] = c1*TW[t] + c2*RW[t] + 0.5*(TW[t-1] - RW[t-1]);  c1,c2 = (0.5,0.5) for
// t < T-1, (1,0) at t = T-1; prev-term dropped at t = 0.
// Weight staging per tile: 64 rows x 64 cols fp32 = 16KB/array ->
// 4 float4 loads/thread/array (lo=0..3 covers rows lo*16+wrow, wrow=tid>>4).
template <int TMPOUT>
__global__ __launch_bounds__(256, 1) void gemm_kernel(const unsigned short* __restrict__ At2,
                                                      const float* __restrict__ TW,
                                                      const float* __restrict__ RW,
                                                      const float* __restrict__ tb,
                                                      const float* __restrict__ rb,
                                                      float* __restrict__ out,
                                                      unsigned short* __restrict__ tmp) {
  __shared__ float rawT[64 * 64];           // [t][n] fp32, pitch 64 (reads are lane-across-n)
  __shared__ float rawR[64 * 64];
  __shared__ unsigned short vT[64 * 72];    // V^T bf16, [n][t], pitch 72 shorts
  __shared__ float prevT[2][64], prevR[2][64];

  const int tid = threadIdx.x;
  // XCD chunk swizzle: grid 256, 8 XCDs -> 32 consecutive bids per XCD
  // (= 2 f-panels per XCD; At2 panels 2x512KB stay L2-resident).
  const int bid = (blockIdx.x & 7) * 32 + (blockIdx.x >> 3);
  const int f  = bid >> 4;
  const int n0 = (bid & 15) * 64;
  const int w = tid >> 6, l = tid & 63;
  const int lrow = l & 15, lg = l >> 4;

  const float* TWf = TW + (size_t)f * (T_ * N_) + n0;
  const float* RWf = RW + (size_t)f * (T_ * N_) + n0;
  const unsigned short* Af2 = At2 + ((size_t)f * 32 * 16 * 512);

  // weight load mapping: load lo covers rows lo*16..lo*16+15 (lo=0..3)
  const int wrow = tid >> 4;           // row 0..15 within each 16-row group
  const int wc   = (tid & 15) * 4;     // col (floats) 0..60

  const int vn = tid & 31, strip = tid >> 5;   // V-compute: 8 strips x 8 t, 2 col-halves

  f32x4 acc[4][4];                     // [nt][m]
#pragma unroll
  for (int nt = 0; nt < 4; ++nt)
#pragma unroll
    for (int m = 0; m < 4; ++m)
      acc[nt][m] = (f32x4){0.f, 0.f, 0.f, 0.f};

  // prologue: load tile 0 weights (regs) + A-frags
  float4 wtT[4], wtR[4];
#pragma unroll
  for (int lo = 0; lo < 4; ++lo) {
    wtT[lo] = *(const float4*)(TWf + (size_t)(lo * 16 + wrow) * N_ + wc);
    wtR[lo] = *(const float4*)(RWf + (size_t)(lo * 16 + wrow) * N_ + wc);
  }
  bf16x8 afrag[2][2][4];
#pragma unroll
  for (int ks = 0; ks < 2; ++ks)
#pragma unroll
    for (int m = 0; m < 4; ++m)
      afrag[0][ks][m] = *(const bf16x8*)(Af2 + (((size_t)(ks * 16) + (w * 4 + m)) << 9) + l * 8);

#pragma unroll 1
  for (int kt = 0; kt < 16; ++kt) {
    const int k0 = kt * 64;
    __syncthreads();   // previous tile's vT / raw LDS fully consumed
    // commit staged weight regs -> LDS (waits on the outstanding loads)
#pragma unroll
    for (int lo = 0; lo < 4; ++lo) {
      *(float4*)&rawT[(lo * 16 + wrow) * 64 + wc] = wtT[lo];
      *(float4*)&rawR[(lo * 16 + wrow) * 64 + wc] = wtR[lo];
    }
    __syncthreads();   // raw ready
    // issue next tile's loads EARLY (drained at next step's LDS commit;
    // covered by V-compute + MFMA below)
    if (kt < 15) {
#pragma unroll
      for (int lo = 0; lo < 4; ++lo) {
        wtT[lo] = *(const float4*)(TWf + (size_t)(k0 + 64 + lo * 16 + wrow) * N_ + wc);
        wtR[lo] = *(const float4*)(RWf + (size_t)(k0 + 64 + lo * 16 + wrow) * N_ + wc);
      }
#pragma unroll
      for (int ks = 0; ks < 2; ++ks)
#pragma unroll
        for (int m = 0; m < 4; ++m)
          afrag[(kt + 1) & 1][ks][m] =
              *(const bf16x8*)(Af2 + (((size_t)((kt + 1) * 2 + ks) * 16 + (w * 4 + m)) << 9) + l * 8);
    }
    // ---- V-compute: 2 col-halves x (32 n-lanes x 8 strips of 8 t) ----
#pragma unroll
    for (int half = 0; half < 2; ++half) {
      const int col = half * 32 + vn;
      float ptw, prw;
      if (strip == 0) { ptw = prevT[(kt & 1) ^ 1][col]; prw = prevR[(kt & 1) ^ 1][col]; }
      else            { ptw = rawT[(strip * 8 - 1) * 64 + col]; prw = rawR[(strip * 8 - 1) * 64 + col]; }
      unsigned pk[4];
      unsigned lo32 = 0;
      float tw = 0.f, rw = 0.f;
#pragma unroll
      for (int i = 0; i < 8; ++i) {
        const int t = strip * 8 + i, tg = k0 + t;
        tw = rawT[t * 64 + col]; rw = rawR[t * 64 + col];
        const float c1 = (tg < T_ - 1) ? 0.5f : 1.0f;
        const float c2 = (tg < T_ - 1) ? 0.5f : 0.0f;
        const float pterm = (tg >= 1) ? 0.5f * (ptw - prw) : 0.0f;
        const unsigned short us = f2bf(c1 * tw + c2 * rw + pterm);
        if ((i & 1) == 0) lo32 = us; else pk[i >> 1] = lo32 | ((unsigned)us << 16);
        ptw = tw; prw = rw;
      }
      uint4 q; q.x = pk[0]; q.y = pk[1]; q.z = pk[2]; q.w = pk[3];
      *(uint4*)&vT[col * 72 + strip * 8] = q;
      if (strip == 7) { prevT[kt & 1][col] = tw; prevR[kt & 1][col] = rw; }
    }
    __syncthreads();   // vT ready
    // ---- MFMA: 2 ks x 4 nt x 4 m, A-frags reused across nt ----
#pragma unroll
    for (int ks = 0; ks < 2; ++ks) {
#pragma unroll
      for (int nt = 0; nt < 4; ++nt) {
        bf16x8 bfrag = *(const bf16x8*)&vT[(nt * 16 + lrow) * 72 + ks * 32 + lg * 8];
#pragma unroll
        for (int m = 0; m < 4; ++m)
          acc[nt][m] = __builtin_amdgcn_mfma_f32_16x16x32_bf16(afrag[kt & 1][ks][m], bfrag, acc[nt][m], 0, 0, 0);
      }
    }
  }

  // ---- epilogue: bias + store ----
#pragma unroll
  for (int nt = 0; nt < 4; ++nt) {
    const int n = n0 + nt * 16 + lrow;
    const float bsum = tb[f * N_ + n] + rb[f * N_ + n];
#pragma unroll
    for (int m = 0; m < 4; ++m) {
#pragma unroll
      for (int j = 0; j < 4; ++j) {
        const int brow = w * 64 + m * 16 + lg * 4 + j;
        const float v = acc[nt][m][j] + bsum;
        if (TMPOUT) {
          tmp[((size_t)f * B_ + brow) * N_ + n] = f2bf(v);          // coalesced 32B segments
        } else {
          out[((size_t)brow * N_ + n) * F_ + f] = v;                // scattered fallback
        }
      }
    }
  }
}

// ---- pass 3: tmp[F][B][N] bf16 -> out[B][N][F] fp32, coalesced both sides ----
__global__ __launch_bounds__(256) void untile_kernel(const unsigned short* __restrict__ tmp,
                                                     float* __restrict__ out) {
  __shared__ unsigned short ld[16 * 1048];   // [f][n], padded pitch
  const int b = blockIdx.x, tid = threadIdx.x;
#pragma unroll
  for (int it = 0; it < 8; ++it) {
    const int idx = it * 256 + tid;
    const int f = idx >> 7, c = idx & 127;
    uint4 v = *(const uint4*)(tmp + ((size_t)f * B_ + b) * N_ + c * 8);
    *(uint4*)&ld[f * 1048 + c * 8] = v;
  }
  __syncthreads();
  float* ob = out + (size_t)b * (N_ * F_);
#pragma unroll
  for (int it = 0; it < 16; ++it) {
    const int g = it * 256 + tid;
    const int n = g >> 2, f0 = (g & 3) * 4;
    float4 o;
    o.x = bf2f(ld[(f0 + 0) * 1048 + n]);
    o.y = bf2f(ld[(f0 + 1) * 1048 + n]);
    o.z = bf2f(ld[(f0 + 2) * 1048 + n]);
    o.w = bf2f(ld[(f0 + 3) * 1048 + n]);
    *(float4*)(ob + n * F_ + f0) = o;
  }
}

extern "C" void kernel_launch(void* const* d_in, const int* in_sizes, int n_in,
                              void* d_out, int out_size, void* d_ws, size_t ws_size,
                              hipStream_t stream) {
  const float* x  = (const float*)d_in[0];
  const float* TW = (const float*)d_in[8];
  const float* tb = (const float*)d_in[9];
  const float* RW = (const float*)d_in[10];
  const float* rb = (const float*)d_in[11];
  float* out = (float*)d_out;

  unsigned short* At2 = (unsigned short*)d_ws;                // 8 MB
  const size_t atBytes  = (size_t)F_ * B_ * T_ * sizeof(unsigned short);
  const size_t tmpBytes = (size_t)F_ * B_ * N_ * sizeof(unsigned short);

  prep2_kernel<<<256, 256, 0, stream>>>(x, At2);
  if (ws_size >= atBytes + tmpBytes) {
    unsigned short* tmp = (unsigned short*)((char*)d_ws + atBytes);
    gemm_kernel<1><<<256, 256, 0, stream>>>(At2, TW, RW, tb, rb, out, tmp);
    untile_kernel<<<256, 256, 0, stream>>>(tmp, out);
  } else {
    gemm_kernel<0><<<256, 256, 0, stream>>>(At2, TW, RW, tb, rb, out, nullptr);
  }
}

// Round 9
// 41.848 us; speedup vs baseline: 2.6978x; 2.6978x over previous
//
#include <hip/hip_runtime.h>
#include <hip/hip_bf16.h>
#include <stdint.h>

#define B_  256
#define T_  1024
#define F_  16
#define N_  1024

typedef short bf16x8 __attribute__((ext_vector_type(8)));
typedef float f32x4  __attribute__((ext_vector_type(4)));

static __device__ __forceinline__ unsigned short f2bf(float x) {
  unsigned u = __builtin_bit_cast(unsigned, x);
  u += 0x7fffu + ((u >> 16) & 1u);
  return (unsigned short)(u >> 16);
}
static __device__ __forceinline__ float bf2f(unsigned short h) {
  unsigned u = ((unsigned)h) << 16;
  return __builtin_bit_cast(float, u);
}

// ---- pass 1: x[b][t][f] fp32 -> At2 fragment layout bf16 ----
// At2 element (f,b,k) at ((f*32+kc)*16+rb)*512 + lane*8 + j, where
// kc=k>>5, rb=b>>4, lane=((k>>3)&3)*16 + (b&15), j=k&7.
__global__ __launch_bounds__(256) void prep2_kernel(const float* __restrict__ x,
                                                    unsigned short* __restrict__ At2) {
  __shared__ unsigned short ld[16 * 1028];   // [b_local][t_local*16+f], pitch 1028
  const int rb = blockIdx.x >> 4, tc = blockIdx.x & 15;
  const int tid = threadIdx.x;
  const int tl = tid >> 2;            // t-local 0..63
  const int f4 = (tid & 3) * 4;       // f quad
#pragma unroll
  for (int i = 0; i < 16; ++i) {
    const float* src = x + (((size_t)(rb * 16 + i) * T_) + tc * 64 + tl) * F_ + f4;
    float4 v = *(const float4*)src;
    uint2 pk;
    pk.x = (unsigned)f2bf(v.x) | ((unsigned)f2bf(v.y) << 16);
    pk.y = (unsigned)f2bf(v.z) | ((unsigned)f2bf(v.w) << 16);
    *(uint2*)&ld[i * 1028 + tl * 16 + f4] = pk;
  }
  __syncthreads();
  const int w = tid >> 6, l = tid & 63;
#pragma unroll
  for (int it = 0; it < 8; ++it) {
    const int c = it * 4 + w;          // 0..31 = (f, kcl)
    const int f = c >> 1, kcl = c & 1;
    unsigned short t16[8];
#pragma unroll
    for (int j = 0; j < 8; ++j)
      t16[j] = ld[(l & 15) * 1028 + (kcl * 32 + ((l >> 4) * 8) + j) * 16 + f];
    uint4 q;
    q.x = (unsigned)t16[0] | ((unsigned)t16[1] << 16);
    q.y = (unsigned)t16[2] | ((unsigned)t16[3] << 16);
    q.z = (unsigned)t16[4] | ((unsigned)t16[5] << 16);
    q.w = (unsigned)t16[6] | ((unsigned)t16[7] << 16);
    *(uint4*)(At2 + (((size_t)(f * 32 + tc * 2 + kcl) * 16 + rb) << 9) + l * 8) = q;
  }
}

// ---- pass 2: fused GEMM, EBN=64, 1024-thread blocks (16 waves, m-frag = wave) ----
// acc[b,n] = sum_t x_bf16[b,t,f] * V[f,t,n]
// V[t] = c1*TW[t] + c2*RW[t] + 0.5*(TW[t-1] - RW[t-1]);  c1,c2 = (0.5,0.5) for
// t < T-1, (1,0) at t = T-1; prev-term dropped at t = 0.
// Per tile: each thread stages ONE float4 of each weight array (64x64 tile =
// 1024 threads x 16B); wave w loads 2 At2 chunks (1KB, coalesced) and runs
// 2ks x 4nt MFMA on its 16 rows. kt loop fully unrolled -> all frag indices
// static (no scratch; rule #20).
template <int TMPOUT>
__global__ __launch_bounds__(1024) void gemm_kernel(const unsigned short* __restrict__ At2,
                                                    const float* __restrict__ TW,
                                                    const float* __restrict__ RW,
                                                    const float* __restrict__ tb,
                                                    const float* __restrict__ rb,
                                                    float* __restrict__ out,
                                                    unsigned short* __restrict__ tmp) {
  __shared__ float rawT[64 * 64];           // [t][n] fp32 (V-reads are lane-across-n, stride-1)
  __shared__ float rawR[64 * 64];
  __shared__ unsigned short vT[64 * 72];    // V^T bf16, [n][t], pitch 72 shorts
  __shared__ float prevT[2][64], prevR[2][64];

  const int tid = threadIdx.x;
  // XCD chunk swizzle: grid 256, 8 XCDs -> 32 consecutive bids per XCD
  // (= 2 f-panels per XCD; At2 panels 2x512KB stay L2-resident).
  const int bid = (blockIdx.x & 7) * 32 + (blockIdx.x >> 3);
  const int f  = bid >> 4;
  const int n0 = (bid & 15) * 64;
  const int w = tid >> 6, l = tid & 63;     // wave 0..15, lane 0..63
  const int lrow = l & 15, lg = l >> 4;

  const float* TWf = TW + (size_t)f * (T_ * N_) + n0;
  const float* RWf = RW + (size_t)f * (T_ * N_) + n0;
  const unsigned short* Af2 = At2 + ((size_t)f * 32 * 16 * 512);

  // weight staging: one float4 per thread per array; rows 0..63 x cols 0..60
  const int wrow = tid >> 4;           // 0..63
  const int wc   = (tid & 15) * 4;     // 0..60 (floats)

  f32x4 acc[4];                        // [nt], m-frag = w
#pragma unroll
  for (int nt = 0; nt < 4; ++nt)
    acc[nt] = (f32x4){0.f, 0.f, 0.f, 0.f};

  // prologue: load tile 0 weights (regs) + A-frags
  float4 wtT = *(const float4*)(TWf + (size_t)wrow * N_ + wc);
  float4 wtR = *(const float4*)(RWf + (size_t)wrow * N_ + wc);
  bf16x8 afrag[2][2];                  // [buf][ks]
#pragma unroll
  for (int ks = 0; ks < 2; ++ks)
    afrag[0][ks] = *(const bf16x8*)(Af2 + (((size_t)(ks * 16 + w)) << 9) + l * 8);

#pragma unroll
  for (int kt = 0; kt < 16; ++kt) {
    const int k0 = kt * 64;
    __syncthreads();   // previous tile's vT / raw LDS fully consumed
    // commit staged weight regs -> LDS (vmcnt waits only on own loads)
    *(float4*)&rawT[wrow * 64 + wc] = wtT;
    *(float4*)&rawR[wrow * 64 + wc] = wtR;
    __syncthreads();   // raw ready
    // issue next tile's loads EARLY (drained at next iter's commit; covered
    // by V-compute + MFMA below)
    if (kt < 15) {
      wtT = *(const float4*)(TWf + (size_t)(k0 + 64 + wrow) * N_ + wc);
      wtR = *(const float4*)(RWf + (size_t)(k0 + 64 + wrow) * N_ + wc);
#pragma unroll
      for (int ks = 0; ks < 2; ++ks)
        afrag[(kt + 1) & 1][ks] =
            *(const bf16x8*)(Af2 + (((size_t)(((kt + 1) * 2 + ks) * 16 + w)) << 9) + l * 8);
    }
    // ---- V-compute: wave w = t-strip w (4 rows), lane = n-col (stride-1) ----
    {
      float ptw, prw;
      if (w == 0) { ptw = prevT[(kt & 1) ^ 1][l]; prw = prevR[(kt & 1) ^ 1][l]; }
      else        { ptw = rawT[(w * 4 - 1) * 64 + l]; prw = rawR[(w * 4 - 1) * 64 + l]; }
      unsigned pk[2];
      unsigned lo32 = 0;
      float tw = 0.f, rw = 0.f;
#pragma unroll
      for (int i = 0; i < 4; ++i) {
        const int t = w * 4 + i, tg = k0 + t;
        tw = rawT[t * 64 + l]; rw = rawR[t * 64 + l];
        const float c1 = (tg < T_ - 1) ? 0.5f : 1.0f;
        const float c2 = (tg < T_ - 1) ? 0.5f : 0.0f;
        const float pterm = (tg >= 1) ? 0.5f * (ptw - prw) : 0.0f;
        const unsigned short us = f2bf(c1 * tw + c2 * rw + pterm);
        if ((i & 1) == 0) lo32 = us; else pk[i >> 1] = lo32 | ((unsigned)us << 16);
        ptw = tw; prw = rw;
      }
      uint2 q; q.x = pk[0]; q.y = pk[1];
      *(uint2*)&vT[l * 72 + w * 4] = q;
      if (w == 15) { prevT[kt & 1][l] = tw; prevR[kt & 1][l] = rw; }
    }
    __syncthreads();   // vT ready
    // ---- MFMA: 2 ks x 4 nt (m-frag = w) ----
#pragma unroll
    for (int ks = 0; ks < 2; ++ks) {
#pragma unroll
      for (int nt = 0; nt < 4; ++nt) {
        bf16x8 bfrag = *(const bf16x8*)&vT[(nt * 16 + lrow) * 72 + ks * 32 + lg * 8];
        acc[nt] = __builtin_amdgcn_mfma_f32_16x16x32_bf16(afrag[kt & 1][ks], bfrag, acc[nt], 0, 0, 0);
      }
    }
  }

  // ---- epilogue: bias + store (wave w owns rows w*16..w*16+15) ----
#pragma unroll
  for (int nt = 0; nt < 4; ++nt) {
    const int n = n0 + nt * 16 + lrow;
    const float bsum = tb[f * N_ + n] + rb[f * N_ + n];
#pragma unroll
    for (int j = 0; j < 4; ++j) {
      const int brow = w * 16 + lg * 4 + j;
      const float v = acc[nt][j] + bsum;
      if (TMPOUT) {
        tmp[((size_t)f * B_ + brow) * N_ + n] = f2bf(v);          // coalesced 32B segments
      } else {
        out[((size_t)brow * N_ + n) * F_ + f] = v;                // scattered fallback
      }
    }
  }
}

// ---- pass 3: tmp[F][B][N] bf16 -> out[B][N][F] fp32, coalesced both sides ----
__global__ __launch_bounds__(256) void untile_kernel(const unsigned short* __restrict__ tmp,
                                                     float* __restrict__ out) {
  __shared__ unsigned short ld[16 * 1048];   // [f][n], padded pitch
  const int b = blockIdx.x, tid = threadIdx.x;
#pragma unroll
  for (int it = 0; it < 8; ++it) {
    const int idx = it * 256 + tid;
    const int f = idx >> 7, c = idx & 127;
    uint4 v = *(const uint4*)(tmp + ((size_t)f * B_ + b) * N_ + c * 8);
    *(uint4*)&ld[f * 1048 + c * 8] = v;
  }
  __syncthreads();
  float* ob = out + (size_t)b * (N_ * F_);
#pragma unroll
  for (int it = 0; it < 16; ++it) {
    const int g = it * 256 + tid;
    const int n = g >> 2, f0 = (g & 3) * 4;
    float4 o;
    o.x = bf2f(ld[(f0 + 0) * 1048 + n]);
    o.y = bf2f(ld[(f0 + 1) * 1048 + n]);
    o.z = bf2f(ld[(f0 + 2) * 1048 + n]);
    o.w = bf2f(ld[(f0 + 3) * 1048 + n]);
    *(float4*)(ob + n * F_ + f0) = o;
  }
}

extern "C" void kernel_launch(void* const* d_in, const int* in_sizes, int n_in,
                              void* d_out, int out_size, void* d_ws, size_t ws_size,
                              hipStream_t stream) {
  const float* x  = (const float*)d_in[0];
  const float* TW = (const float*)d_in[8];
  const float* tb = (const float*)d_in[9];
  const float* RW = (const float*)d_in[10];
  const float* rb = (const float*)d_in[11];
  float* out = (float*)d_out;

  unsigned short* At2 = (unsigned short*)d_ws;                // 8 MB
  const size_t atBytes  = (size_t)F_ * B_ * T_ * sizeof(unsigned short);
  const size_t tmpBytes = (size_t)F_ * B_ * N_ * sizeof(unsigned short);

  prep2_kernel<<<256, 256, 0, stream>>>(x, At2);
  if (ws_size >= atBytes + tmpBytes) {
    unsigned short* tmp = (unsigned short*)((char*)d_ws + atBytes);
    gemm_kernel<1><<<256, 1024, 0, stream>>>(At2, TW, RW, tb, rb, out, tmp);
    untile_kernel<<<256, 256, 0, stream>>>(tmp, out);
  } else {
    gemm_kernel<0><<<256, 1024, 0, stream>>>(At2, TW, RW, tb, rb, out, nullptr);
  }
}